// Round 5
// baseline (232.366 us; speedup 1.0000x reference)
//
#include <hip/hip_runtime.h>
#include <hip/hip_cooperative_groups.h>

namespace cg = cooperative_groups;

static constexpr int N = 128;
static constexpr int F = 128;
static constexpr int H = 8;
static constexpr int NATTR = 3;
static constexpr int M = N * N;        // 16384
static constexpr int OUTW = 320;       // F + 8*16 + 8*8
static constexpr int MSL = 32;         // m-splits in edge attention
static constexpr int HG = 2;           // heads per edge-attn block
static constexpr int EABLK = (H / HG) * 8 * MSL;  // 1024 virtual blocks
static constexpr float LOG2E = 1.4426950408889634f;

__device__ __forceinline__ float leaky(float x) { return fmaxf(x, 0.2f * x); }

struct Params {
    const float *X, *A, *E, *adj;
    const float *Wn0, *bn0, *an0s, *an0n;
    const float *Wn1, *bn1, *an1s, *an1n;
    const float *We0, *be0, *We1, *be1;
    const float *Wct0, *bct0, *Wct1, *bct1;
    const float *ae0s, *ae0n, *ae1s, *ae1n;
    float* out;
    float *feat, *aself, *fe0, *ae0e, *fe1, *ae1e, *part, *wvec, *einfo, *xh;
};

// ---------------------------------------------------------------------------
// Edge-to-node attention phase. Virtual block = (head-pair, n-tile 16,
// m-chunk 512), covers all 3 attrs. L1 computes a_self inline from xh·wvec.
// exp2-based (logit terms pre-scaled by log2e). Partials to `part`.
template <int KE, bool L1>
__device__ __forceinline__ void ea_body(
    const float* __restrict__ fe,      // [8][M][KE]
    const float* __restrict__ ae,      // [8][M]  (scaled)
    const float* __restrict__ a_self,  // [3][8][N] (scaled) | L0
    const float* __restrict__ xh,      // [3][N][128]        | L1
    const float* __restrict__ wvec,    // [3][8][128] scaled | L1
    const float* __restrict__ adj,     // [N][M]
    float* __restrict__ part) {        // [3][8][N][MSL][8]
    constexpr int CH = M / MSL;        // 512
    int tid = threadIdx.x;
    int r = tid >> 4, l = tid & 15;

    for (int b = blockIdx.x; b < EABLK; b += gridDim.x) {
        int ms = b & (MSL - 1);
        int nt = (b >> 5) & 7;
        int h0 = (b >> 8) * HG;
        int n = nt * 16 + r;
        int m0 = ms * CH;

        float as[NATTR][HG];
        if (!L1) {
#pragma unroll
            for (int a = 0; a < NATTR; ++a)
#pragma unroll
                for (int hh = 0; hh < HG; ++hh)
                    as[a][hh] = a_self[(a * H + h0 + hh) * N + n];
        } else {
#pragma unroll
            for (int a = 0; a < NATTR; ++a) {
                const float* xr = xh + (size_t)(a * N + n) * F;
                float xv[8];
#pragma unroll
                for (int j = 0; j < 8; ++j) xv[j] = xr[l + 16 * j];
#pragma unroll
                for (int hh = 0; hh < HG; ++hh) {
                    const float* wr = wvec + (size_t)(a * H + h0 + hh) * F;
                    float d = 0.f;
#pragma unroll
                    for (int j = 0; j < 8; ++j) d += xv[j] * wr[l + 16 * j];
#pragma unroll
                    for (int off = 1; off < 16; off <<= 1) d += __shfl_xor(d, off);
                    as[a][hh] = d;
                }
            }
        }

        const float* adjp = adj + (size_t)n * M + m0;
        const float* aep[HG];
        const float* fep[HG];
#pragma unroll
        for (int hh = 0; hh < HG; ++hh) {
            aep[hh] = ae + (size_t)(h0 + hh) * M + m0;
            fep[hh] = fe + ((size_t)(h0 + hh) * M + m0) * KE;
        }

        float sum[HG][NATTR];
        float acc[HG][NATTR][KE];
#pragma unroll
        for (int hh = 0; hh < HG; ++hh)
#pragma unroll
            for (int a = 0; a < NATTR; ++a) {
                sum[hh][a] = 0.f;
#pragma unroll
                for (int k = 0; k < KE; ++k) acc[hh][a][k] = 0.f;
            }

        for (int i = l * 4; i < CH; i += 64) {
            const float4 av = *(const float4*)(adjp + i);
            float4 ev[HG];
            float fv[HG][4][KE];
#pragma unroll
            for (int hh = 0; hh < HG; ++hh) {
                ev[hh] = *(const float4*)(aep[hh] + i);
#pragma unroll
                for (int j = 0; j < 4; ++j) {
                    if (KE == 4) {
                        const float4 fq = *(const float4*)(fep[hh] + (i + j) * 4);
                        fv[hh][j][0] = fq.x; fv[hh][j][1] = fq.y;
                        fv[hh][j][2] = fq.z; fv[hh][j][3] = fq.w;
                    } else {
                        const float2 fq = *(const float2*)(fep[hh] + (i + j) * 2);
                        fv[hh][j][0] = fq.x; fv[hh][j][1] = fq.y;
                    }
                }
            }
#pragma unroll
            for (int j = 0; j < 4; ++j) {
                float adjv = reinterpret_cast<const float*>(&av)[j] * LOG2E;
#pragma unroll
                for (int hh = 0; hh < HG; ++hh) {
                    float aev = reinterpret_cast<const float*>(&ev[hh])[j];
#pragma unroll
                    for (int a = 0; a < NATTR; ++a) {
                        float t = as[a][hh] + aev;
                        float p = __builtin_amdgcn_exp2f(fmaxf(t, 0.2f * t) + adjv);
                        sum[hh][a] += p;
#pragma unroll
                        for (int k = 0; k < KE; ++k) acc[hh][a][k] += p * fv[hh][j][k];
                    }
                }
            }
        }

#pragma unroll
        for (int off = 1; off < 16; off <<= 1) {
#pragma unroll
            for (int hh = 0; hh < HG; ++hh)
#pragma unroll
                for (int a = 0; a < NATTR; ++a) {
                    sum[hh][a] += __shfl_xor(sum[hh][a], off);
#pragma unroll
                    for (int k = 0; k < KE; ++k) acc[hh][a][k] += __shfl_xor(acc[hh][a][k], off);
                }
        }
        if (l == 0) {
#pragma unroll
            for (int hh = 0; hh < HG; ++hh)
#pragma unroll
                for (int a = 0; a < NATTR; ++a) {
                    float* pp = part + (((size_t)(a * H + h0 + hh) * N + n) * MSL + ms) * 8;
#pragma unroll
                    for (int k = 0; k < KE; ++k) pp[k] = acc[hh][a][k];
                    pp[7] = sum[hh][a];
                }
        }
    }
}

// ---------------------------------------------------------------------------
// Tail phase: virtual block = (a, h, itile of 16 rows). Assembles nf_e,
// computes feat2 (LDS), s2/n2, dE/cE, then 16 rows of node attn + elu + out.
template <int K, int KE, bool L1>
__device__ __forceinline__ void tail_body(
    float* smem, const float* __restrict__ feat, const float* __restrict__ xh,
    const float* __restrict__ Wn1, const float* __restrict__ part,
    const float* __restrict__ be, const float* __restrict__ Wct,
    const float* __restrict__ bct, const float* __restrict__ ans,
    const float* __restrict__ ann, const float* __restrict__ Einfo,
    const float* __restrict__ Amat, const float* __restrict__ bn,
    float* __restrict__ out, int outOff,
    float* __restrict__ xh_out, float* __restrict__ einfo_out) {
    constexpr int CIN = K + KE;
    float* sW     = smem;          // 320
    float* sIn    = smem + 320;    // 2560
    float* sOut   = smem + 2880;   // 2048
    float* sS2    = smem + 4928;   // 128
    float* sn2    = smem + 5056;   // 128
    float* sdE    = smem + 5184;   // 128
    float* scE    = smem + 5312;   // 128
    float* sAlpha = smem + 5440;   // 512 = [4][128]
    float* sRed   = smem + 5952;   // 256
    float* sWn1   = smem + 6208;   // 2048
    int tid = threadIdx.x;

    for (int b = blockIdx.x; b < 192; b += gridDim.x) {
        int itile = b & 7, h = (b >> 3) & 7, a = b >> 6;

        // ---- phase 0: weights + sIn assembly ----
        for (int i = tid; i < CIN * K; i += 256) sW[i] = Wct[h * CIN * K + i];
        if (L1)
            for (int i = tid; i < F * K; i += 256)
                sWn1[i] = Wn1[(size_t)(a * H + h) * F * K + i];
        if (tid < N) {
            int n = tid;
            const float* pp = part + ((size_t)(a * H + h) * N + n) * MSL * 8;
            float av[4] = {0.f, 0.f, 0.f, 0.f};
            float sv = 0.f;
            for (int ms = 0; ms < MSL; ++ms) {
                const float4 x = *(const float4*)(pp + ms * 8);
                const float4 y = *(const float4*)(pp + ms * 8 + 4);
                av[0] += x.x; av[1] += x.y;
                if (KE == 4) { av[2] += x.z; av[3] += x.w; }
                sv += y.w;
            }
            float inv = 1.f / sv;
#pragma unroll
            for (int k = 0; k < KE; ++k)
                sIn[n * CIN + K + k] = av[k] * inv + be[h * KE + k];
        }
        if (!L1) {
            for (int i = tid; i < N * K; i += 256) {
                int n = i / K, k = i % K;
                sIn[n * CIN + k] = feat[((a * H + h) * N + n) * 16 + k];
            }
        } else {
            __syncthreads();   // sWn1 ready
            for (int o = tid; o < N * K; o += 256) {
                int n = o / K, k = o % K;
                const float* xr = xh + (size_t)(a * N + n) * F;
                float acc = 0.f;
                for (int f = 0; f < F; ++f) acc += xr[f] * sWn1[f * K + k];
                sIn[n * CIN + k] = acc;
            }
        }
        __syncthreads();

        // ---- phase 1: feat2 = sIn @ Wct + bct ----
        for (int o = tid; o < N * K; o += 256) {
            int n = o / K, k = o % K;
            float acc = bct[h * K + k];
            for (int c = 0; c < CIN; ++c) acc += sIn[n * CIN + c] * sW[c * K + k];
            sOut[o] = acc;
        }
        __syncthreads();
        if (tid < N) {
            int n = tid;
            float ss = 0.f, nn = 0.f;
            for (int k = 0; k < K; ++k) {
                ss += sOut[n * K + k] * ans[(a * H + h) * K + k];
                nn += sOut[n * K + k] * ann[(a * H + h) * K + k];
            }
            sS2[n] = ss;
            sn2[n] = nn;
        }
        __syncthreads();

        // ---- phase 2: dE[m] = n2·Einfo[:,m], cE = colsum(Einfo) ----
        {
            int m = tid & 127, w = tid >> 7;
            const float* Ep = Einfo + (size_t)a * M;
            float dacc = 0.f, cacc = 0.f;
            for (int j = w * 64; j < w * 64 + 64; ++j) {
                float v = Ep[j * N + m];
                dacc += sn2[j] * v;
                cacc += v;
            }
            sRed[tid] = dacc;
            sAlpha[w * N + m] = cacc;
            __syncthreads();
            if (tid < N) {
                sdE[tid] = sRed[tid] + sRed[128 + tid];
                scE[tid] = sAlpha[tid] + sAlpha[N + tid];
            }
        }
        __syncthreads();

        // ---- phase 3: node attention, 4 passes x 4 rows (1 wave/row) ----
        for (int pass = 0; pass < 4; ++pass) {
            int r = tid >> 6;
            int lane = tid & 63;
            int i = itile * 16 + pass * 4 + r;
            float s = sS2[i];
            const float* Ap = Amat + ((size_t)a * N + i) * N;
            float v0 = leaky(s * scE[lane] + sdE[lane]) + Ap[lane];
            float v1 = leaky(s * scE[lane + 64] + sdE[lane + 64]) + Ap[lane + 64];
            float p0 = __expf(v0), p1 = __expf(v1);
            float ssum = p0 + p1;
#pragma unroll
            for (int off = 1; off < 64; off <<= 1) ssum += __shfl_xor(ssum, off);
            float inv = 1.f / ssum;
            float a0 = p0 * inv, a1 = p1 * inv;
            sAlpha[r * N + lane] = a0;
            sAlpha[r * N + lane + 64] = a1;
            if (einfo_out != nullptr && h == H - 1) {
                einfo_out[((size_t)a * N + i) * N + lane] = a0;
                einfo_out[((size_t)a * N + i) * N + lane + 64] = a1;
            }
            __syncthreads();
            {
                int rr = tid >> 6, g = (tid >> 4) & 3, k = tid & 15;
                float acc = 0.f;
                if (k < K) {
                    for (int it = 0; it < 32; ++it) {
                        int mm = g + 4 * it;
                        acc += sAlpha[rr * N + mm] * sOut[mm * K + k];
                    }
                }
                sRed[tid] = acc;
            }
            __syncthreads();
            {
                int rr = tid >> 6, k = tid & 63;
                if (k < K) {
                    float tot = bn[(a * H + h) * K + k];
#pragma unroll
                    for (int g = 0; g < 4; ++g) tot += sRed[rr * 64 + g * 16 + k];
                    float e = tot > 0.f ? tot : __expf(tot) - 1.f;   // elu
                    int i2 = itile * 16 + pass * 4 + rr;
                    out[(i2 * NATTR + a) * OUTW + outOff + h * K + k] = e;
                    if (xh_out != nullptr)
                        xh_out[((size_t)a * N + i2) * F + h * K + k] = e;
                }
            }
            __syncthreads();
        }
    }
}

// ---------------------------------------------------------------------------
// Single persistent cooperative kernel: front -> ea0 -> tail0 -> ea1 -> tail1
__global__ void __launch_bounds__(256, 2) k_fused(Params P) {
    __shared__ float smem[8256];
    cg::grid_group grid = cg::this_grid();
    int tid = threadIdx.x;

    // ============ Phase A: front (353 virtual blocks) ============
    for (int vb = blockIdx.x; vb < 353; vb += gridDim.x) {
        if (vb < 64) {
            // ---- edge features, both layers (fe1 = E @ (We0_flat @ We1)) ----
            float* sW0 = smem;            // 96
            float* sA0 = smem + 96;       // 32
            float* sA1 = smem + 128;      // 16
            float* sWc = smem + 144;      // 48
            if (tid < 96) sW0[tid] = P.We0[tid];
            if (tid < 32) sA0[tid] = P.ae0n[tid];
            if (tid < 16) sA1[tid] = P.ae1n[tid];
            __syncthreads();
            if (tid < 48) {
                int h2 = tid / 6;
                int rem = tid % 6;
                int at = rem >> 1, k2 = rem & 1;
                float acc = 0.f;
                for (int c = 0; c < 32; ++c)
                    acc += sW0[((c >> 2) * 3 + at) * 4 + (c & 3)] *
                           P.We1[(h2 * 32 + c) * 2 + k2];
                sWc[(h2 * 3 + at) * 2 + k2] = acc;
            }
            __syncthreads();
            int m = vb * 256 + tid;
            float e0 = P.E[m], e1 = P.E[M + m], e2 = P.E[2 * M + m];
            for (int h = 0; h < H; ++h) {
                float4 v;
                float* vp = &v.x;
                float aa = 0.f;
#pragma unroll
                for (int ke = 0; ke < 4; ++ke) {
                    float f = e0 * sW0[(h * 3 + 0) * 4 + ke] +
                              e1 * sW0[(h * 3 + 1) * 4 + ke] +
                              e2 * sW0[(h * 3 + 2) * 4 + ke];
                    vp[ke] = f;
                    aa += f * sA0[h * 4 + ke];
                }
                *(float4*)&P.fe0[(size_t)(h * M + m) * 4] = v;
                P.ae0e[h * M + m] = aa * LOG2E;
                float f0 = e0 * sWc[(h * 3 + 0) * 2 + 0] + e1 * sWc[(h * 3 + 1) * 2 + 0] +
                           e2 * sWc[(h * 3 + 2) * 2 + 0];
                float f1 = e0 * sWc[(h * 3 + 0) * 2 + 1] + e1 * sWc[(h * 3 + 1) * 2 + 1] +
                           e2 * sWc[(h * 3 + 2) * 2 + 1];
                *(float2*)&P.fe1[(size_t)(h * M + m) * 2] = make_float2(f0, f1);
                P.ae1e[h * M + m] = (f0 * sA1[h * 2 + 0] + f1 * sA1[h * 2 + 1]) * LOG2E;
            }
        } else if (vb < 256) {
            // ---- out[:, a, 0:128] = X ----
            int idx = (vb - 64) * 256 + tid;
            int f = idx & (F - 1);
            int rest = idx >> 7;
            int a = rest % NATTR;
            int n = rest / NATTR;
            P.out[(n * NATTR + a) * OUTW + f] = P.X[n * F + f];
        } else if (vb < 352) {
            // ---- layer-0 node features, n-tiled 4x (K=16) ----
            constexpr int K = 16;
            int vb2 = vb - 256;            // [0,96)
            int a = vb2 >> 5;
            int h = (vb2 >> 2) & 7;
            int n0 = (vb2 & 3) * 32;
            const float* Wp = P.Wn0 + (size_t)(a * H + h) * F * K;
            float* sW = smem;              // 2048
            float* sF = smem + 2048;       // 512
            for (int i = tid; i < F * K; i += 256) sW[i] = Wp[i];
            __syncthreads();
#pragma unroll
            for (int o = tid; o < 32 * K; o += 256) {
                int n = n0 + (o >> 4), k = o & 15;
                const float* xr = P.X + n * F;
                float acc = 0.f;
                for (int f = 0; f < F; ++f) acc += xr[f] * sW[f * K + k];
                sF[o] = acc;
                P.feat[((a * H + h) * N + n) * 16 + k] = acc;
            }
            __syncthreads();
            if (tid < 32) {
                float acc = 0.f;
                for (int k = 0; k < K; ++k) acc += sF[tid * K + k] * P.ae0s[h * K + k];
                P.aself[(a * H + h) * N + n0 + tid] = acc * LOG2E;
            }
        } else {
            // ---- wvec = log2e * (Wn1 @ ae1s) ----
            for (int o = tid; o < NATTR * H * F; o += 256) {
                int f = o & (F - 1);
                int ah = o >> 7;
                int h = ah & 7;
                float acc = 0.f;
#pragma unroll
                for (int k = 0; k < 8; ++k)
                    acc += P.Wn1[((size_t)ah * F + f) * 8 + k] * P.ae1s[h * 8 + k];
                P.wvec[o] = acc * LOG2E;
            }
        }
        __syncthreads();   // guard smem reuse across virtual blocks
    }
    grid.sync();

    // ============ Phase B: edge attention layer 0 ============
    ea_body<4, false>(P.fe0, P.ae0e, P.aself, nullptr, nullptr, P.adj, P.part);
    grid.sync();

    // ============ Phase C: tail layer 0 ============
    tail_body<16, 4, false>(smem, P.feat, nullptr, nullptr, P.part, P.be0,
                            P.Wct0, P.bct0, P.an0s, P.an0n, P.E, P.A, P.bn0,
                            P.out, F, P.xh, P.einfo);
    grid.sync();

    // ============ Phase D: edge attention layer 1 ============
    ea_body<2, true>(P.fe1, P.ae1e, nullptr, P.xh, P.wvec, P.adj, P.part);
    grid.sync();

    // ============ Phase E: tail layer 1 ============
    tail_body<8, 2, true>(smem, nullptr, P.xh, P.Wn1, P.part, P.be1,
                          P.Wct1, P.bct1, P.an1s, P.an1n, P.einfo, P.A, P.bn1,
                          P.out, F + 128, nullptr, nullptr);
}

// ---------------------------------------------------------------------------
extern "C" void kernel_launch(void* const* d_in, const int* in_sizes, int n_in,
                              void* d_out, int out_size, void* d_ws, size_t ws_size,
                              hipStream_t stream) {
    Params prm;
    prm.X    = (const float*)d_in[0];
    prm.A    = (const float*)d_in[1];
    prm.E    = (const float*)d_in[2];
    prm.adj  = (const float*)d_in[3];
    prm.Wn0  = (const float*)d_in[4];
    prm.bn0  = (const float*)d_in[5];
    prm.an0s = (const float*)d_in[6];
    prm.an0n = (const float*)d_in[7];
    prm.Wn1  = (const float*)d_in[8];
    prm.bn1  = (const float*)d_in[9];
    prm.an1s = (const float*)d_in[10];
    prm.an1n = (const float*)d_in[11];
    prm.We0  = (const float*)d_in[12];
    prm.be0  = (const float*)d_in[13];
    prm.We1  = (const float*)d_in[14];
    prm.be1  = (const float*)d_in[15];
    prm.Wct0 = (const float*)d_in[16];
    prm.bct0 = (const float*)d_in[17];
    prm.Wct1 = (const float*)d_in[18];
    prm.bct1 = (const float*)d_in[19];
    prm.ae0s = (const float*)d_in[20];
    prm.ae0n = (const float*)d_in[21];
    prm.ae1s = (const float*)d_in[22];
    prm.ae1n = (const float*)d_in[23];
    prm.out  = (float*)d_out;

    float* p = (float*)d_ws;
    prm.feat  = p; p += NATTR * H * N * 16;
    prm.aself = p; p += NATTR * H * N;
    prm.fe0   = p; p += H * M * 4;
    prm.ae0e  = p; p += H * M;
    prm.fe1   = p; p += H * M * 2;
    prm.ae1e  = p; p += H * M;
    prm.part  = p; p += (size_t)NATTR * H * N * MSL * 8;
    prm.wvec  = p; p += NATTR * H * F;
    prm.einfo = p; p += NATTR * N * N;
    prm.xh    = p; p += NATTR * N * F;

    int occ = 0;
    hipOccupancyMaxActiveBlocksPerMultiprocessor(&occ, k_fused, 256, 0);
    if (occ < 1) occ = 1;
    int grid = occ * 256;          // 256 CUs on MI355X
    if (grid > EABLK) grid = EABLK;

    void* args[] = {(void*)&prm};
    hipLaunchCooperativeKernel(k_fused, dim3(grid), dim3(256), args, 0u, stream);
}

// Round 6
// 110.422 us; speedup vs baseline: 2.1043x; 2.1043x over previous
//
#include <hip/hip_runtime.h>

static constexpr int N = 128;
static constexpr int F = 128;
static constexpr int H = 8;
static constexpr int NATTR = 3;
static constexpr int M = N * N;        // 16384
static constexpr int OUTW = 320;       // F + 8*16 + 8*8
static constexpr int MSL = 32;         // m-splits in edge attention
static constexpr int CH = M / MSL;     // 512
static constexpr float LOG2E = 1.4426950408889634f;

__device__ __forceinline__ float leaky(float x) { return fmaxf(x, 0.2f * x); }

// ---------------------------------------------------------------------------
// Edge-to-node attention, self-sufficient. Block = (head-quad hq, n-tile 16,
// m-chunk 512), covers all 3 attrs x 4 heads. Stages fe/ae for its chunk in
// LDS (computed from E), computes wvec -> a_self inline. exp2-based.
// Partials (acc[KE], sum) to `part`.
template <int KE, bool L1>
__global__ void __launch_bounds__(256)
k_ea(const float* __restrict__ E,      // [3][N][N]
     const float* __restrict__ xsrc,   // X (stride 0) | xh [3][N][128]
     int xStride,
     const float* __restrict__ Wn,     // [3][8][F][KW]
     const float* __restrict__ aes,    // [8][KW]
     const float* __restrict__ We0,    // [8][3][4]
     const float* __restrict__ aen,    // [8][KE]  (ae0n | ae1n)
     const float* __restrict__ We1,    // [8][32][2] (L1 only)
     const float* __restrict__ adj,    // [N][M]
     float* __restrict__ part) {       // [3][8][N][MSL][8]
    constexpr int KW = L1 ? 8 : 16;
    __shared__ __align__(16) float sFe[4 * CH * KE];
    __shared__ __align__(16) float sAe[4 * CH];
    __shared__ __align__(16) float sWv[12 * 128];
    __shared__ __align__(16) float sWc[48];

    int b = blockIdx.x;
    int ms = b & (MSL - 1);
    int nt = (b >> 5) & 7;
    int h0 = (b >> 8) * 4;
    int tid = threadIdx.x;
    int r = tid >> 4, l = tid & 15;
    int n = nt * 16 + r;
    int m0 = ms * CH;

    // ---- stage wvec[c][f] = log2e * sum_k Wn[a][h][f][k]*aes[h][k] ----
    for (int idx = tid; idx < 12 * 128; idx += 256) {
        int c = idx >> 7, f = idx & 127;
        int a = c >> 2, h = h0 + (c & 3);
        const float* wp = Wn + ((size_t)(a * H + h) * F + f) * KW;
        const float* ap = aes + h * KW;
        float acc = 0.f;
#pragma unroll
        for (int k = 0; k < KW; ++k) acc += wp[k] * ap[k];
        sWv[idx] = acc * LOG2E;
    }
    // ---- stage Wcomb (L1): [4h][3][2] ----
    if (L1) {
        if (tid < 24) {
            int hh = tid / 6, rem = tid % 6, at = rem >> 1, k2 = rem & 1;
            int h = h0 + hh;
            float acc = 0.f;
            for (int c = 0; c < 32; ++c)
                acc += We0[((c >> 2) * 3 + at) * 4 + (c & 3)] *
                       We1[(h * 32 + c) * 2 + k2];
            sWc[(hh * 3 + at) * 2 + k2] = acc;
        }
        __syncthreads();
    }
    // ---- stage fe/ae for the chunk: [4h][512] ----
    for (int idx = tid; idx < 4 * CH; idx += 256) {
        int hh = idx >> 9, mm = idx & (CH - 1);
        int m = m0 + mm, h = h0 + hh;
        float e0 = E[m], e1 = E[M + m], e2 = E[2 * M + m];
        if (!L1) {
            float aa = 0.f;
#pragma unroll
            for (int k = 0; k < 4; ++k) {
                float f = e0 * We0[(h * 3 + 0) * 4 + k] +
                          e1 * We0[(h * 3 + 1) * 4 + k] +
                          e2 * We0[(h * 3 + 2) * 4 + k];
                sFe[(hh * CH + mm) * 4 + k] = f;
                aa += f * aen[h * 4 + k];
            }
            sAe[hh * CH + mm] = aa * LOG2E;
        } else {
            float f0 = e0 * sWc[(hh * 3 + 0) * 2 + 0] + e1 * sWc[(hh * 3 + 1) * 2 + 0] +
                       e2 * sWc[(hh * 3 + 2) * 2 + 0];
            float f1 = e0 * sWc[(hh * 3 + 0) * 2 + 1] + e1 * sWc[(hh * 3 + 1) * 2 + 1] +
                       e2 * sWc[(hh * 3 + 2) * 2 + 1];
            sFe[(hh * CH + mm) * 2 + 0] = f0;
            sFe[(hh * CH + mm) * 2 + 1] = f1;
            sAe[hh * CH + mm] = (f0 * aen[h * 2 + 0] + f1 * aen[h * 2 + 1]) * LOG2E;
        }
    }
    __syncthreads();

    // ---- a_self inline: lane-coop dot of x-row with sWv ----
    float as[NATTR][4];
#pragma unroll
    for (int a = 0; a < NATTR; ++a) {
        const float* xr = xsrc + (size_t)a * xStride + (size_t)n * F;
        float xv[8];
#pragma unroll
        for (int j = 0; j < 8; ++j) xv[j] = xr[l + 16 * j];
#pragma unroll
        for (int hh = 0; hh < 4; ++hh) {
            const float* wr = sWv + (a * 4 + hh) * 128;
            float d = 0.f;
#pragma unroll
            for (int j = 0; j < 8; ++j) d += xv[j] * wr[l + 16 * j];
#pragma unroll
            for (int off = 1; off < 16; off <<= 1) d += __shfl_xor(d, off);
            as[a][hh] = d;
        }
    }

    // ---- main loop over the 512-m chunk ----
    float sum[4][NATTR];
    float acc[4][NATTR][KE];
#pragma unroll
    for (int hh = 0; hh < 4; ++hh)
#pragma unroll
        for (int a = 0; a < NATTR; ++a) {
            sum[hh][a] = 0.f;
#pragma unroll
            for (int k = 0; k < KE; ++k) acc[hh][a][k] = 0.f;
        }

    const float* adjp = adj + (size_t)n * M + m0;
    for (int i = l * 4; i < CH; i += 64) {
        const float4 av = *(const float4*)(adjp + i);
        float4 ev[4];
#pragma unroll
        for (int hh = 0; hh < 4; ++hh)
            ev[hh] = *(const float4*)&sAe[hh * CH + i];
#pragma unroll
        for (int j = 0; j < 4; ++j) {
            float adjv = (&av.x)[j] * LOG2E;
#pragma unroll
            for (int hh = 0; hh < 4; ++hh) {
                float aev = (&ev[hh].x)[j];
                float fv[KE];
                if (KE == 4) {
                    const float4 fq = *(const float4*)&sFe[(hh * CH + i + j) * 4];
                    fv[0] = fq.x; fv[1] = fq.y; fv[2] = fq.z; fv[3] = fq.w;
                } else {
                    const float2 fq = *(const float2*)&sFe[(hh * CH + i + j) * 2];
                    fv[0] = fq.x; fv[1] = fq.y;
                }
#pragma unroll
                for (int a = 0; a < NATTR; ++a) {
                    float t = as[a][hh] + aev;
                    float p = __builtin_amdgcn_exp2f(fmaxf(t, 0.2f * t) + adjv);
                    sum[hh][a] += p;
#pragma unroll
                    for (int k = 0; k < KE; ++k) acc[hh][a][k] += p * fv[k];
                }
            }
        }
    }

    // ---- butterfly-reduce within each 16-lane row group, write partials ----
#pragma unroll
    for (int off = 1; off < 16; off <<= 1) {
#pragma unroll
        for (int hh = 0; hh < 4; ++hh)
#pragma unroll
            for (int a = 0; a < NATTR; ++a) {
                sum[hh][a] += __shfl_xor(sum[hh][a], off);
#pragma unroll
                for (int k = 0; k < KE; ++k) acc[hh][a][k] += __shfl_xor(acc[hh][a][k], off);
            }
    }
    if (l == 0) {
#pragma unroll
        for (int hh = 0; hh < 4; ++hh)
#pragma unroll
            for (int a = 0; a < NATTR; ++a) {
                float* pp = part + (((size_t)(a * H + h0 + hh) * N + n) * MSL + ms) * 8;
#pragma unroll
                for (int k = 0; k < KE; ++k) pp[k] = acc[hh][a][k];
                pp[7] = sum[hh][a];
            }
    }
}

// ---------------------------------------------------------------------------
// Tail: per (a, h, itile of 16 rows). Inline feat = xsrc @ Wn (LDS weights),
// assembles nf_e from partials, feat2, s2/n2, dE/cE, node attention + elu.
// FIRST also copies X into out's first 128 cols (h==0 blocks).
template <int K, int KE, bool FIRST>
__global__ void __launch_bounds__(256)
k_tail(const float* __restrict__ xsrc,    // X (stride 0) | xh
       int xStride,
       const float* __restrict__ Wn,      // [3][8][F][K]
       const float* __restrict__ part,    // [3][8][N][MSL][8]
       const float* __restrict__ be,      // [8][KE]
       const float* __restrict__ Wct,     // [8][K+KE][K]
       const float* __restrict__ bct,     // [8][K]
       const float* __restrict__ ans,     // [3][8][K]
       const float* __restrict__ ann,     // [3][8][K]
       const float* __restrict__ Einfo,   // [3][N][N]
       const float* __restrict__ Amat,    // [3][N][N]
       const float* __restrict__ bn,      // [3][8][K]
       const float* __restrict__ X,       // for FIRST copy
       float* __restrict__ out, int outOff,
       float* __restrict__ xh_out,        // [3][N][128] or nullptr
       float* __restrict__ einfo_out) {   // [3][N][N] or nullptr
    constexpr int CIN = K + KE;
    __shared__ __align__(16) float sW[CIN * K];
    __shared__ __align__(16) float sIn[N * CIN];
    __shared__ __align__(16) float sOut[N * K];
    __shared__ __align__(16) float sS2[N];
    __shared__ __align__(16) float sn2[N];
    __shared__ __align__(16) float sdE[N];
    __shared__ __align__(16) float scE[N];
    __shared__ __align__(16) float sAlpha[4 * N];
    __shared__ __align__(16) float sRed[256];
    __shared__ __align__(16) float sWn[F * K];

    int b = blockIdx.x;
    int itile = b & 7, h = (b >> 3) & 7, a = b >> 6;
    int tid = threadIdx.x;

    // ---- phase 0: stage weights + part-reduce nf_e ----
    for (int i = tid; i < CIN * K; i += 256) sW[i] = Wct[h * CIN * K + i];
    for (int i = tid; i < F * K; i += 256)
        sWn[i] = Wn[(size_t)(a * H + h) * F * K + i];
    if (tid < N) {
        int n = tid;
        const float* pp = part + ((size_t)(a * H + h) * N + n) * MSL * 8;
        float av[4] = {0.f, 0.f, 0.f, 0.f};
        float sv = 0.f;
        for (int ms = 0; ms < MSL; ++ms) {
            const float4 x = *(const float4*)(pp + ms * 8);
            const float4 y = *(const float4*)(pp + ms * 8 + 4);
            av[0] += x.x; av[1] += x.y;
            if (KE == 4) { av[2] += x.z; av[3] += x.w; }
            sv += y.w;
        }
        float inv = 1.f / sv;
#pragma unroll
        for (int k = 0; k < KE; ++k)
            sIn[n * CIN + K + k] = av[k] * inv + be[h * KE + k];
    }
    // X -> out copy (FIRST, h==0 blocks; covers all (n,a) across blocks)
    if (FIRST && h == 0) {
        for (int i = tid; i < 16 * F; i += 256) {
            int n = itile * 16 + (i >> 7);
            int f = i & (F - 1);
            out[(n * NATTR + a) * OUTW + f] = X[n * F + f];
        }
    }
    __syncthreads();
    // ---- inline feat = xsrc @ Wn ----
    for (int o = tid; o < N * K; o += 256) {
        int n = o / K, k = o % K;
        const float* xr = xsrc + (size_t)a * xStride + (size_t)n * F;
        float acc = 0.f;
        for (int f = 0; f < F; ++f) acc += xr[f] * sWn[f * K + k];
        sIn[n * CIN + k] = acc;
    }
    __syncthreads();

    // ---- phase 1: feat2 = sIn @ Wct + bct; s2/n2 ----
    for (int o = tid; o < N * K; o += 256) {
        int n = o / K, k = o % K;
        float acc = bct[h * K + k];
        for (int c = 0; c < CIN; ++c) acc += sIn[n * CIN + c] * sW[c * K + k];
        sOut[o] = acc;
    }
    __syncthreads();
    if (tid < N) {
        int n = tid;
        float ss = 0.f, nn = 0.f;
        for (int k = 0; k < K; ++k) {
            ss += sOut[n * K + k] * ans[(a * H + h) * K + k];
            nn += sOut[n * K + k] * ann[(a * H + h) * K + k];
        }
        sS2[n] = ss;
        sn2[n] = nn;
    }
    __syncthreads();

    // ---- phase 2: dE[m] = n2·Einfo[:,m], cE = colsum(Einfo) ----
    {
        int m = tid & 127, w = tid >> 7;
        const float* Ep = Einfo + (size_t)a * M;
        float dacc = 0.f, cacc = 0.f;
        for (int j = w * 64; j < w * 64 + 64; ++j) {
            float v = Ep[j * N + m];
            dacc += sn2[j] * v;
            cacc += v;
        }
        sRed[tid] = dacc;
        sAlpha[w * N + m] = cacc;
        __syncthreads();
        if (tid < N) {
            sdE[tid] = sRed[tid] + sRed[128 + tid];
            scE[tid] = sAlpha[tid] + sAlpha[N + tid];
        }
    }
    __syncthreads();

    // ---- phase 3: node attention, 4 passes x 4 rows (1 wave/row) ----
    for (int pass = 0; pass < 4; ++pass) {
        int r = tid >> 6;
        int lane = tid & 63;
        int i = itile * 16 + pass * 4 + r;
        float s = sS2[i];
        const float* Ap = Amat + ((size_t)a * N + i) * N;
        float v0 = leaky(s * scE[lane] + sdE[lane]) + Ap[lane];
        float v1 = leaky(s * scE[lane + 64] + sdE[lane + 64]) + Ap[lane + 64];
        float p0 = __expf(v0), p1 = __expf(v1);
        float ssum = p0 + p1;
#pragma unroll
        for (int off = 1; off < 64; off <<= 1) ssum += __shfl_xor(ssum, off);
        float inv = 1.f / ssum;
        float a0 = p0 * inv, a1 = p1 * inv;
        sAlpha[r * N + lane] = a0;
        sAlpha[r * N + lane + 64] = a1;
        if (einfo_out != nullptr && h == H - 1) {
            einfo_out[((size_t)a * N + i) * N + lane] = a0;
            einfo_out[((size_t)a * N + i) * N + lane + 64] = a1;
        }
        __syncthreads();
        {
            int rr = tid >> 6, g = (tid >> 4) & 3, k = tid & 15;
            float acc = 0.f;
            if (k < K) {
                for (int it = 0; it < 32; ++it) {
                    int mm = g + 4 * it;
                    acc += sAlpha[rr * N + mm] * sOut[mm * K + k];
                }
            }
            sRed[tid] = acc;
        }
        __syncthreads();
        {
            int rr = tid >> 6, k = tid & 63;
            if (k < K) {
                float tot = bn[(a * H + h) * K + k];
#pragma unroll
                for (int g = 0; g < 4; ++g) tot += sRed[rr * 64 + g * 16 + k];
                float e = tot > 0.f ? tot : __expf(tot) - 1.f;   // elu
                int i2 = itile * 16 + pass * 4 + rr;
                out[(i2 * NATTR + a) * OUTW + outOff + h * K + k] = e;
                if (xh_out != nullptr)
                    xh_out[((size_t)a * N + i2) * F + h * K + k] = e;
            }
        }
        __syncthreads();
    }
}

// ---------------------------------------------------------------------------
extern "C" void kernel_launch(void* const* d_in, const int* in_sizes, int n_in,
                              void* d_out, int out_size, void* d_ws, size_t ws_size,
                              hipStream_t stream) {
    const float* X    = (const float*)d_in[0];
    const float* A    = (const float*)d_in[1];
    const float* E    = (const float*)d_in[2];
    const float* adj  = (const float*)d_in[3];
    const float* Wn0  = (const float*)d_in[4];
    const float* bn0  = (const float*)d_in[5];
    const float* an0s = (const float*)d_in[6];
    const float* an0n = (const float*)d_in[7];
    const float* Wn1  = (const float*)d_in[8];
    const float* bn1  = (const float*)d_in[9];
    const float* an1s = (const float*)d_in[10];
    const float* an1n = (const float*)d_in[11];
    const float* We0  = (const float*)d_in[12];
    const float* be0  = (const float*)d_in[13];
    const float* We1  = (const float*)d_in[14];
    const float* be1  = (const float*)d_in[15];
    const float* Wct0 = (const float*)d_in[16];
    const float* bct0 = (const float*)d_in[17];
    const float* Wct1 = (const float*)d_in[18];
    const float* bct1 = (const float*)d_in[19];
    const float* ae0s = (const float*)d_in[20];
    const float* ae0n = (const float*)d_in[21];
    const float* ae1s = (const float*)d_in[22];
    const float* ae1n = (const float*)d_in[23];
    float* out = (float*)d_out;

    float* p = (float*)d_ws;
    float* part  = p; p += (size_t)NATTR * H * N * MSL * 8;
    float* einfo = p; p += NATTR * N * N;
    float* xh    = p; p += NATTR * N * F;

    // ---- layer 0 ----
    k_ea<4, false><<<dim3(512), dim3(256), 0, stream>>>(
        E, X, 0, Wn0, ae0s, We0, ae0n, nullptr, adj, part);
    k_tail<16, 4, true><<<dim3(192), dim3(256), 0, stream>>>(
        X, 0, Wn0, part, be0, Wct0, bct0, an0s, an0n, E, A, bn0, X,
        out, F, xh, einfo);

    // ---- layer 1 ----
    k_ea<2, true><<<dim3(512), dim3(256), 0, stream>>>(
        E, xh, N * F, Wn1, ae1s, We0, ae1n, We1, adj, part);
    k_tail<8, 2, false><<<dim3(192), dim3(256), 0, stream>>>(
        xh, N * F, Wn1, part, be1, Wct1, bct1, an1s, an1n, einfo, A, bn1,
        nullptr, out, F + 128, nullptr, nullptr);
}

// Round 7
// 86.292 us; speedup vs baseline: 2.6928x; 1.2796x over previous
//
#include <hip/hip_runtime.h>

static constexpr int N = 128;
static constexpr int F = 128;
static constexpr int H = 8;
static constexpr int NATTR = 3;
static constexpr int M = N * N;        // 16384
static constexpr int OUTW = 320;       // F + 8*16 + 8*8
static constexpr int MSL = 32;         // m-splits in edge attention
static constexpr int CH = M / MSL;     // 512
static constexpr float LOG2E = 1.4426950408889634f;

__device__ __forceinline__ float leaky(float x) { return fmaxf(x, 0.2f * x); }

// ---------------------------------------------------------------------------
// Edge-to-node attention, self-sufficient (unchanged from R6). Block =
// (head-quad, n-tile 16, m-chunk 512), covers all 3 attrs x 4 heads.
template <int KE, bool L1>
__global__ void __launch_bounds__(256)
k_ea(const float* __restrict__ E,      // [3][N][N]
     const float* __restrict__ xsrc,   // X (stride 0) | xh [3][N][128]
     int xStride,
     const float* __restrict__ Wn,     // [3][8][F][KW]
     const float* __restrict__ aes,    // [8][KW]
     const float* __restrict__ We0,    // [8][3][4]
     const float* __restrict__ aen,    // [8][KE]
     const float* __restrict__ We1,    // [8][32][2] (L1 only)
     const float* __restrict__ adj,    // [N][M]
     float* __restrict__ part) {       // [3][8][N][MSL][8]
    constexpr int KW = L1 ? 8 : 16;
    __shared__ __align__(16) float sFe[4 * CH * KE];
    __shared__ __align__(16) float sAe[4 * CH];
    __shared__ __align__(16) float sWv[12 * 128];
    __shared__ __align__(16) float sWc[48];

    int b = blockIdx.x;
    int ms = b & (MSL - 1);
    int nt = (b >> 5) & 7;
    int h0 = (b >> 8) * 4;
    int tid = threadIdx.x;
    int r = tid >> 4, l = tid & 15;
    int n = nt * 16 + r;
    int m0 = ms * CH;

    for (int idx = tid; idx < 12 * 128; idx += 256) {
        int c = idx >> 7, f = idx & 127;
        int a = c >> 2, h = h0 + (c & 3);
        const float* wp = Wn + ((size_t)(a * H + h) * F + f) * KW;
        const float* ap = aes + h * KW;
        float acc = 0.f;
#pragma unroll
        for (int k = 0; k < KW; ++k) acc += wp[k] * ap[k];
        sWv[idx] = acc * LOG2E;
    }
    if (L1) {
        if (tid < 24) {
            int hh = tid / 6, rem = tid % 6, at = rem >> 1, k2 = rem & 1;
            int h = h0 + hh;
            float acc = 0.f;
            for (int c = 0; c < 32; ++c)
                acc += We0[((c >> 2) * 3 + at) * 4 + (c & 3)] *
                       We1[(h * 32 + c) * 2 + k2];
            sWc[(hh * 3 + at) * 2 + k2] = acc;
        }
        __syncthreads();
    }
    for (int idx = tid; idx < 4 * CH; idx += 256) {
        int hh = idx >> 9, mm = idx & (CH - 1);
        int m = m0 + mm, h = h0 + hh;
        float e0 = E[m], e1 = E[M + m], e2 = E[2 * M + m];
        if (!L1) {
            float aa = 0.f;
#pragma unroll
            for (int k = 0; k < 4; ++k) {
                float f = e0 * We0[(h * 3 + 0) * 4 + k] +
                          e1 * We0[(h * 3 + 1) * 4 + k] +
                          e2 * We0[(h * 3 + 2) * 4 + k];
                sFe[(hh * CH + mm) * 4 + k] = f;
                aa += f * aen[h * 4 + k];
            }
            sAe[hh * CH + mm] = aa * LOG2E;
        } else {
            float f0 = e0 * sWc[(hh * 3 + 0) * 2 + 0] + e1 * sWc[(hh * 3 + 1) * 2 + 0] +
                       e2 * sWc[(hh * 3 + 2) * 2 + 0];
            float f1 = e0 * sWc[(hh * 3 + 0) * 2 + 1] + e1 * sWc[(hh * 3 + 1) * 2 + 1] +
                       e2 * sWc[(hh * 3 + 2) * 2 + 1];
            sFe[(hh * CH + mm) * 2 + 0] = f0;
            sFe[(hh * CH + mm) * 2 + 1] = f1;
            sAe[hh * CH + mm] = (f0 * aen[h * 2 + 0] + f1 * aen[h * 2 + 1]) * LOG2E;
        }
    }
    __syncthreads();

    float as[NATTR][4];
#pragma unroll
    for (int a = 0; a < NATTR; ++a) {
        const float* xr = xsrc + (size_t)a * xStride + (size_t)n * F;
        float xv[8];
#pragma unroll
        for (int j = 0; j < 8; ++j) xv[j] = xr[l + 16 * j];
#pragma unroll
        for (int hh = 0; hh < 4; ++hh) {
            const float* wr = sWv + (a * 4 + hh) * 128;
            float d = 0.f;
#pragma unroll
            for (int j = 0; j < 8; ++j) d += xv[j] * wr[l + 16 * j];
#pragma unroll
            for (int off = 1; off < 16; off <<= 1) d += __shfl_xor(d, off);
            as[a][hh] = d;
        }
    }

    float sum[4][NATTR];
    float acc[4][NATTR][KE];
#pragma unroll
    for (int hh = 0; hh < 4; ++hh)
#pragma unroll
        for (int a = 0; a < NATTR; ++a) {
            sum[hh][a] = 0.f;
#pragma unroll
            for (int k = 0; k < KE; ++k) acc[hh][a][k] = 0.f;
        }

    const float* adjp = adj + (size_t)n * M + m0;
    for (int i = l * 4; i < CH; i += 64) {
        const float4 av = *(const float4*)(adjp + i);
        float4 ev[4];
#pragma unroll
        for (int hh = 0; hh < 4; ++hh)
            ev[hh] = *(const float4*)&sAe[hh * CH + i];
#pragma unroll
        for (int j = 0; j < 4; ++j) {
            float adjv = (&av.x)[j] * LOG2E;
#pragma unroll
            for (int hh = 0; hh < 4; ++hh) {
                float aev = (&ev[hh].x)[j];
                float fv[KE];
                if (KE == 4) {
                    const float4 fq = *(const float4*)&sFe[(hh * CH + i + j) * 4];
                    fv[0] = fq.x; fv[1] = fq.y; fv[2] = fq.z; fv[3] = fq.w;
                } else {
                    const float2 fq = *(const float2*)&sFe[(hh * CH + i + j) * 2];
                    fv[0] = fq.x; fv[1] = fq.y;
                }
#pragma unroll
                for (int a = 0; a < NATTR; ++a) {
                    float t = as[a][hh] + aev;
                    float p = __builtin_amdgcn_exp2f(fmaxf(t, 0.2f * t) + adjv);
                    sum[hh][a] += p;
#pragma unroll
                    for (int k = 0; k < KE; ++k) acc[hh][a][k] += p * fv[k];
                }
            }
        }
    }

#pragma unroll
    for (int off = 1; off < 16; off <<= 1) {
#pragma unroll
        for (int hh = 0; hh < 4; ++hh)
#pragma unroll
            for (int a = 0; a < NATTR; ++a) {
                sum[hh][a] += __shfl_xor(sum[hh][a], off);
#pragma unroll
                for (int k = 0; k < KE; ++k) acc[hh][a][k] += __shfl_xor(acc[hh][a][k], off);
            }
    }
    if (l == 0) {
#pragma unroll
        for (int hh = 0; hh < 4; ++hh)
#pragma unroll
            for (int a = 0; a < NATTR; ++a) {
                float* pp = part + (((size_t)(a * H + h0 + hh) * N + n) * MSL + ms) * 8;
#pragma unroll
                for (int k = 0; k < KE; ++k) pp[k] = acc[hh][a][k];
                pp[7] = sum[hh][a];
            }
    }
}

// ---------------------------------------------------------------------------
// Mid: block = (a, h, ntile of 32 rows) = 96 blocks. Reduces part ONCE,
// inline feat for its 32 rows only, feat2 = [feat|nf_e]@Wct + bct, s2/n2.
// FIRST blocks (h==0) also copy X into out's first 128 cols.
template <int K, int KE, bool FIRST>
__global__ void __launch_bounds__(256)
k_mid(const float* __restrict__ xsrc,    // X (stride 0) | xh
      int xStride,
      const float* __restrict__ Wn,      // [3][8][F][K]
      const float* __restrict__ part,    // [3][8][N][MSL][8]
      const float* __restrict__ be,      // [8][KE]
      const float* __restrict__ Wct,     // [8][K+KE][K]
      const float* __restrict__ bct,     // [8][K]
      const float* __restrict__ ans,     // [3][8][K]
      const float* __restrict__ ann,     // [3][8][K]
      const float* __restrict__ X,       // FIRST copy src
      float* __restrict__ out,
      float* __restrict__ feat2,         // [3][8][N][16]
      float* __restrict__ s2,            // [3][8][N]
      float* __restrict__ n2) {          // [3][8][N]
    constexpr int CIN = K + KE;
    __shared__ __align__(16) float sWn[F * K];
    __shared__ __align__(16) float sW[CIN * K];
    __shared__ __align__(16) float sIn[32 * CIN];
    __shared__ __align__(16) float sF2[32 * K];

    int b = blockIdx.x;
    int nt = b & 3, h = (b >> 2) & 7, a = b >> 5;
    int n0 = nt * 32;
    int tid = threadIdx.x;

    for (int i = tid; i < F * K; i += 256)
        sWn[i] = Wn[(size_t)(a * H + h) * F * K + i];
    for (int i = tid; i < CIN * K; i += 256) sW[i] = Wct[h * CIN * K + i];

    // ---- part reduce: 32 rows x 8 groups ----
    {
        int r = tid >> 3, g = tid & 7;
        int n = n0 + r;
        const float* pp = part + ((size_t)(a * H + h) * N + n) * MSL * 8;
        float av[4] = {0.f, 0.f, 0.f, 0.f};
        float sv = 0.f;
        for (int ms = g; ms < MSL; ms += 8) {
            const float4 x = *(const float4*)(pp + ms * 8);
            const float4 y = *(const float4*)(pp + ms * 8 + 4);
            av[0] += x.x; av[1] += x.y;
            if (KE == 4) { av[2] += x.z; av[3] += x.w; }
            sv += y.w;
        }
#pragma unroll
        for (int off = 1; off < 8; off <<= 1) {
#pragma unroll
            for (int k = 0; k < KE; ++k) av[k] += __shfl_xor(av[k], off);
            sv += __shfl_xor(sv, off);
        }
        if (g == 0) {
            float inv = 1.f / sv;
#pragma unroll
            for (int k = 0; k < KE; ++k)
                sIn[r * CIN + K + k] = av[k] * inv + be[h * KE + k];
        }
    }
    if (FIRST && h == 0) {
        for (int i = tid; i < 32 * F; i += 256) {
            int n = n0 + (i >> 7);
            int f = i & (F - 1);
            out[(n * NATTR + a) * OUTW + f] = X[n * F + f];
        }
    }
    __syncthreads();

    // ---- inline feat for the 32 rows ----
    for (int o = tid; o < 32 * K; o += 256) {
        int r = o / K, k = o % K;
        const float* xr = xsrc + (size_t)a * xStride + (size_t)(n0 + r) * F;
        float acc = 0.f;
        for (int f = 0; f < F; ++f) acc += xr[f] * sWn[f * K + k];
        sIn[r * CIN + k] = acc;
    }
    __syncthreads();

    // ---- feat2 + s2/n2 ----
    for (int o = tid; o < 32 * K; o += 256) {
        int r = o / K, k = o % K;
        float acc = bct[h * K + k];
        for (int c = 0; c < CIN; ++c) acc += sIn[r * CIN + c] * sW[c * K + k];
        sF2[o] = acc;
        feat2[((size_t)(a * H + h) * N + n0 + r) * 16 + k] = acc;
    }
    __syncthreads();
    if (tid < 32) {
        int r = tid;
        float ss = 0.f, nn = 0.f;
        for (int k = 0; k < K; ++k) {
            ss += sF2[r * K + k] * ans[(a * H + h) * K + k];
            nn += sF2[r * K + k] * ann[(a * H + h) * K + k];
        }
        s2[(a * H + h) * N + n0 + r] = ss;
        n2[(a * H + h) * N + n0 + r] = nn;
    }
}

// ---------------------------------------------------------------------------
// Node: block = (a, h, itile of 16 rows) = 192 blocks. Stages feat2/s2/n2,
// computes dE/cE from Einfo, then node attention + elu + output.
template <int K, bool FIRST>
__global__ void __launch_bounds__(256)
k_node(const float* __restrict__ feat2,   // [3][8][N][16]
       const float* __restrict__ s2,      // [3][8][N]
       const float* __restrict__ n2,      // [3][8][N]
       const float* __restrict__ Einfo,   // [3][N][N]
       const float* __restrict__ Amat,    // [3][N][N]
       const float* __restrict__ bn,      // [3][8][K]
       float* __restrict__ out, int outOff,
       float* __restrict__ xh_out,        // [3][N][128] or nullptr
       float* __restrict__ einfo_out) {   // [3][N][N] or nullptr
    __shared__ __align__(16) float sF2[N * K];
    __shared__ __align__(16) float sS2[N];
    __shared__ __align__(16) float sn2[N];
    __shared__ __align__(16) float sdE[N];
    __shared__ __align__(16) float scE[N];
    __shared__ __align__(16) float sAlpha[4 * N];
    __shared__ __align__(16) float sRed[256];

    int b = blockIdx.x;
    int itile = b & 7, h = (b >> 3) & 7, a = b >> 6;
    int tid = threadIdx.x;

    // ---- stage feat2 / s2 / n2 ----
    for (int i = tid; i < N * K; i += 256)
        sF2[i] = feat2[((size_t)(a * H + h) * N + i / K) * 16 + i % K];
    if (tid < N) {
        sS2[tid] = s2[(a * H + h) * N + tid];
        sn2[tid] = n2[(a * H + h) * N + tid];
    }
    __syncthreads();

    // ---- dE[m] = n2·Einfo[:,m], cE = colsum(Einfo) ----
    {
        int m = tid & 127, w = tid >> 7;
        const float* Ep = Einfo + (size_t)a * M;
        float dacc = 0.f, cacc = 0.f;
        for (int j = w * 64; j < w * 64 + 64; ++j) {
            float v = Ep[j * N + m];
            dacc += sn2[j] * v;
            cacc += v;
        }
        sRed[tid] = dacc;
        sAlpha[w * N + m] = cacc;
        __syncthreads();
        if (tid < N) {
            sdE[tid] = sRed[tid] + sRed[128 + tid];
            scE[tid] = sAlpha[tid] + sAlpha[N + tid];
        }
    }
    __syncthreads();

    // ---- node attention: 4 passes x 4 rows (1 wave/row) ----
    for (int pass = 0; pass < 4; ++pass) {
        int r = tid >> 6;
        int lane = tid & 63;
        int i = itile * 16 + pass * 4 + r;
        float s = sS2[i];
        const float* Ap = Amat + ((size_t)a * N + i) * N;
        float v0 = leaky(s * scE[lane] + sdE[lane]) + Ap[lane];
        float v1 = leaky(s * scE[lane + 64] + sdE[lane + 64]) + Ap[lane + 64];
        float p0 = __expf(v0), p1 = __expf(v1);
        float ssum = p0 + p1;
#pragma unroll
        for (int off = 1; off < 64; off <<= 1) ssum += __shfl_xor(ssum, off);
        float inv = 1.f / ssum;
        float a0 = p0 * inv, a1 = p1 * inv;
        sAlpha[r * N + lane] = a0;
        sAlpha[r * N + lane + 64] = a1;
        if (FIRST && h == H - 1) {
            einfo_out[((size_t)a * N + i) * N + lane] = a0;
            einfo_out[((size_t)a * N + i) * N + lane + 64] = a1;
        }
        __syncthreads();
        {
            int rr = tid >> 6, g = (tid >> 4) & 3, k = tid & 15;
            float acc = 0.f;
            if (k < K) {
                for (int it = 0; it < 32; ++it) {
                    int mm = g + 4 * it;
                    acc += sAlpha[rr * N + mm] * sF2[mm * K + k];
                }
            }
            sRed[tid] = acc;
        }
        __syncthreads();
        {
            int rr = tid >> 6, k = tid & 63;
            if (k < K) {
                float tot = bn[(a * H + h) * K + k];
#pragma unroll
                for (int g = 0; g < 4; ++g) tot += sRed[rr * 64 + g * 16 + k];
                float e = tot > 0.f ? tot : __expf(tot) - 1.f;   // elu
                int i2 = itile * 16 + pass * 4 + rr;
                out[(i2 * NATTR + a) * OUTW + outOff + h * K + k] = e;
                if (FIRST)
                    xh_out[((size_t)a * N + i2) * F + h * K + k] = e;
            }
        }
        __syncthreads();
    }
}

// ---------------------------------------------------------------------------
extern "C" void kernel_launch(void* const* d_in, const int* in_sizes, int n_in,
                              void* d_out, int out_size, void* d_ws, size_t ws_size,
                              hipStream_t stream) {
    const float* X    = (const float*)d_in[0];
    const float* A    = (const float*)d_in[1];
    const float* E    = (const float*)d_in[2];
    const float* adj  = (const float*)d_in[3];
    const float* Wn0  = (const float*)d_in[4];
    const float* bn0  = (const float*)d_in[5];
    const float* an0s = (const float*)d_in[6];
    const float* an0n = (const float*)d_in[7];
    const float* Wn1  = (const float*)d_in[8];
    const float* bn1  = (const float*)d_in[9];
    const float* an1s = (const float*)d_in[10];
    const float* an1n = (const float*)d_in[11];
    const float* We0  = (const float*)d_in[12];
    const float* be0  = (const float*)d_in[13];
    const float* We1  = (const float*)d_in[14];
    const float* be1  = (const float*)d_in[15];
    const float* Wct0 = (const float*)d_in[16];
    const float* bct0 = (const float*)d_in[17];
    const float* Wct1 = (const float*)d_in[18];
    const float* bct1 = (const float*)d_in[19];
    const float* ae0s = (const float*)d_in[20];
    const float* ae0n = (const float*)d_in[21];
    const float* ae1s = (const float*)d_in[22];
    const float* ae1n = (const float*)d_in[23];
    float* out = (float*)d_out;

    float* p = (float*)d_ws;
    float* part  = p; p += (size_t)NATTR * H * N * MSL * 8;
    float* feat2 = p; p += NATTR * H * N * 16;
    float* s2b   = p; p += NATTR * H * N;
    float* n2b   = p; p += NATTR * H * N;
    float* einfo = p; p += NATTR * N * N;
    float* xh    = p; p += NATTR * N * F;

    // ---- layer 0 ----
    k_ea<4, false><<<dim3(512), dim3(256), 0, stream>>>(
        E, X, 0, Wn0, ae0s, We0, ae0n, nullptr, adj, part);
    k_mid<16, 4, true><<<dim3(96), dim3(256), 0, stream>>>(
        X, 0, Wn0, part, be0, Wct0, bct0, an0s, an0n, X, out,
        feat2, s2b, n2b);
    k_node<16, true><<<dim3(192), dim3(256), 0, stream>>>(
        feat2, s2b, n2b, E, A, bn0, out, F, xh, einfo);

    // ---- layer 1 ----
    k_ea<2, true><<<dim3(512), dim3(256), 0, stream>>>(
        E, xh, N * F, Wn1, ae1s, We0, ae1n, We1, adj, part);
    k_mid<8, 2, false><<<dim3(96), dim3(256), 0, stream>>>(
        xh, N * F, Wn1, part, be1, Wct1, bct1, an1s, an1n, nullptr, nullptr,
        feat2, s2b, n2b);
    k_node<8, false><<<dim3(192), dim3(256), 0, stream>>>(
        feat2, s2b, n2b, einfo, A, bn1, out, F + 128, nullptr, nullptr);
}